// Round 4
// baseline (205.543 us; speedup 1.0000x reference)
//
#include <hip/hip_runtime.h>
#include <hip/hip_bf16.h>

// FlashAttentionVarlen, bf16-MFMA flash attention, fp32 in/out.
// B=128 seqs (L in {128,256}), H=16, D=64, packed T=24576.
// Block = (seq b, head h): grid 2048, 512 thr = 8 waves. Each wave owns one
// 16-q-row fragment per 128-row q-tile (1 or 2 q-frags depending on L), so
// K/V are staged ONCE per (b,h) and every K ds_read feeds 2x the MFMAs.
// 64-key tiles, LDS double-buffered (one barrier per tile); K split bf16
// hi/lo (QK error ~2^-17), V bf16-hi, P split hi/lo. Raw s_barrier +
// explicit lgkmcnt(0) keeps prefetch loads in flight across barriers.

using bf16x8 = __attribute__((ext_vector_type(8))) short;
using u16x8  = __attribute__((ext_vector_type(8))) unsigned short;
using f32x4  = __attribute__((ext_vector_type(4))) float;

#define MFMA(a, b, c) __builtin_amdgcn_mfma_f32_16x16x32_bf16((a), (b), (c), 0, 0, 0)

constexpr int H  = 16;
constexpr int D  = 64;
constexpr int RS = H * D;   // packed token row stride in floats

__device__ inline unsigned short bfbits(float x) {
  return __builtin_bit_cast(unsigned short, __float2bfloat16(x));
}
__device__ inline float bff(unsigned short u) {
  return __bfloat162float(__builtin_bit_cast(__hip_bfloat16, u));
}

__global__ __launch_bounds__(512, 4)
void fa_mfma3_kernel(const float* __restrict__ qg, const float* __restrict__ kg,
                     const float* __restrict__ vg, const int* __restrict__ cu,
                     float* __restrict__ outg) {
  // double-buffered planes: K hi/lo [key][d] (slot ^= key&7), V^T [d][key] (slot ^= d&7)
  __shared__ unsigned short kph[2][64 * 64];
  __shared__ unsigned short kpl[2][64 * 64];
  __shared__ unsigned short vth[2][64 * 64];

  const int bid = (int)blockIdx.x;
  const int b = bid >> 4, h = bid & 15;
  const int t0 = cu[b];
  const int L  = cu[b + 1] - t0;
  const bool nq2 = (L > 128);          // 2 q-fragments per wave?
  const int  nt  = L >> 6;             // 64-key tiles: 2 or 4

  const int tid = (int)threadIdx.x, lane = tid & 63, w = tid >> 6;
  const int g = lane >> 4, qj = lane & 15;

  // staging assignments (identical swizzle to verified R3 kernel)
  const int s_key = tid >> 3, s_d0 = (tid & 7) * 8;
  const int kidx  = s_key * 64 + (((s_d0 >> 3) ^ (s_key & 7)) << 3);
  const int s_vd  = tid & 63,  s_k0 = (tid >> 6) * 8;
  const int vidx  = s_vd * 64 + (((s_k0 >> 3) ^ (s_vd & 7)) << 3);

  const float* kbase = kg + (size_t)t0 * RS + h * D;
  const float* vbase = vg + (size_t)t0 * RS + h * D;

  // ---- Q fragments (B operand), split hi/lo, prescaled by 1/8 ----
  bf16x8 qh0[2], ql0[2], qh1[2], ql1[2];
  auto loadQ = [&](int qf, bf16x8 (&qhf)[2], bf16x8 (&qlf)[2]) {
    const float* qrow = qg + (size_t)(t0 + qf * 128 + w * 16 + qj) * RS + h * D;
#pragma unroll
    for (int ks = 0; ks < 2; ++ks) {
      const float4 f0 = *reinterpret_cast<const float4*>(qrow + ks * 32 + g * 8);
      const float4 f1 = *reinterpret_cast<const float4*>(qrow + ks * 32 + g * 8 + 4);
      const float f[8] = {f0.x, f0.y, f0.z, f0.w, f1.x, f1.y, f1.z, f1.w};
#pragma unroll
      for (int j = 0; j < 8; ++j) {
        const float x = f[j] * 0.125f;
        const unsigned short hs = bfbits(x);
        qhf[ks][j] = (short)hs;
        qlf[ks][j] = (short)bfbits(x - bff(hs));
      }
    }
  };
  loadQ(0, qh0, ql0);
  if (nq2) loadQ(1, qh1, ql1);

  f32x4 acc0[4], acc1[4];
#pragma unroll
  for (int n = 0; n < 4; ++n) {
    acc0[n] = (f32x4){0.f, 0.f, 0.f, 0.f};
    acc1[n] = (f32x4){0.f, 0.f, 0.f, 0.f};
  }
  float m0 = -1e30f, l0 = 0.f, m1 = -1e30f, l1 = 0.f;

  // ---- staging: reg prefetch -> cvt -> ds_write (double-buffered LDS) ----
  float4 ka, kb; float va[8];
  u16x8 ch, cl, cv;
  auto load_t = [&](int t) {
    const float* kr = kbase + (size_t)(t * 64 + s_key) * RS + s_d0;
    ka = *reinterpret_cast<const float4*>(kr);
    kb = *reinterpret_cast<const float4*>(kr + 4);
    const float* vp = vbase + (size_t)(t * 64 + s_k0) * RS + s_vd;
#pragma unroll
    for (int i = 0; i < 8; ++i) va[i] = vp[(size_t)i * RS];
  };
  auto cvt_t = [&]() {
    const float kf[8] = {ka.x, ka.y, ka.z, ka.w, kb.x, kb.y, kb.z, kb.w};
#pragma unroll
    for (int i = 0; i < 8; ++i) {
      const unsigned short hs = bfbits(kf[i]);
      ch[i] = hs;
      cl[i] = bfbits(kf[i] - bff(hs));
    }
#pragma unroll
    for (int i = 0; i < 8; ++i) cv[i] = bfbits(va[i]);
  };
  auto write_t = [&](int buf) {
    *reinterpret_cast<u16x8*>(&kph[buf][kidx]) = ch;
    *reinterpret_cast<u16x8*>(&kpl[buf][kidx]) = cl;
    *reinterpret_cast<u16x8*>(&vth[buf][vidx]) = cv;
  };

  // ---- softmax + PV for one q-fragment ----
  auto sm_pv = [&](f32x4 (&sc)[4], float& mf, float& lf, f32x4 (&af)[4],
                   const unsigned short* VT) {
    float tmax = sc[0][0];
#pragma unroll
    for (int kt = 0; kt < 4; ++kt)
#pragma unroll
      for (int r = 0; r < 4; ++r) tmax = fmaxf(tmax, sc[kt][r]);
    tmax = fmaxf(tmax, __shfl_xor(tmax, 16));
    tmax = fmaxf(tmax, __shfl_xor(tmax, 32));
    if (!__all(tmax <= mf + 8.0f)) {        // deferred-max rescale (rare)
      const float newm = fmaxf(mf, tmax);
      const float corr = __expf(mf - newm); // first tile: exp(-inf)=0
      mf = newm;
      lf *= corr;
#pragma unroll
      for (int r = 0; r < 4; ++r) {
        const float cr = __shfl(corr, g * 4 + r);
#pragma unroll
        for (int n = 0; n < 4; ++n) af[n][r] *= cr;
      }
    }
    float p[4][4], ps = 0.f;
#pragma unroll
    for (int kt = 0; kt < 4; ++kt)
#pragma unroll
      for (int r = 0; r < 4; ++r) {
        p[kt][r] = __expf(sc[kt][r] - mf);  // bounded by e^8
        ps += p[kt][r];
      }
    ps += __shfl_xor(ps, 16);
    ps += __shfl_xor(ps, 32);
    lf += ps;
#pragma unroll
    for (int c = 0; c < 2; ++c) {
      bf16x8 pah, pal;
#pragma unroll
      for (int j = 0; j < 8; ++j) {
        const int sl  = (((2 * g + (j >> 2)) & 3) << 4) + qj;
        const float fa = __shfl(p[2 * c][j & 3], sl);
        const float fb = __shfl(p[2 * c + 1][j & 3], sl);
        const float pv = (g & 2) ? fb : fa;
        const unsigned short hb = bfbits(pv);
        pah[j] = (short)hb;
        pal[j] = (short)bfbits(pv - bff(hb));
      }
      __builtin_amdgcn_s_setprio(1);
#pragma unroll
      for (int n = 0; n < 4; ++n) {
        const int idx = (n * 16 + qj) * 64 + (((4 * c + g) ^ (qj & 7)) << 3);
        const bf16x8 vh = *reinterpret_cast<const bf16x8*>(&VT[idx]);
        af[n] = MFMA(pah, vh, af[n]);
        af[n] = MFMA(pal, vh, af[n]);
      }
      __builtin_amdgcn_s_setprio(0);
    }
  };

  // ---- compute one 64-key tile (both q-frags share K/V ds_reads in QK) ----
  auto compute = [&](int buf) {
    const unsigned short* KH = kph[buf];
    const unsigned short* KL = kpl[buf];
    const unsigned short* VT = vth[buf];
    f32x4 sc0[4], sc1[4];
#pragma unroll
    for (int kt = 0; kt < 4; ++kt) {
      sc0[kt] = (f32x4){0.f, 0.f, 0.f, 0.f};
      sc1[kt] = (f32x4){0.f, 0.f, 0.f, 0.f};
    }
    __builtin_amdgcn_s_setprio(1);
#pragma unroll
    for (int kt = 0; kt < 4; ++kt) {
#pragma unroll
      for (int ks = 0; ks < 2; ++ks) {
        const int idx = (kt * 16 + qj) * 64 + (((ks * 4 + g) ^ (qj & 7)) << 3);
        const bf16x8 khi = *reinterpret_cast<const bf16x8*>(&KH[idx]);
        const bf16x8 klo = *reinterpret_cast<const bf16x8*>(&KL[idx]);
        sc0[kt] = MFMA(khi, qh0[ks], sc0[kt]);
        sc0[kt] = MFMA(klo, qh0[ks], sc0[kt]);
        sc0[kt] = MFMA(khi, ql0[ks], sc0[kt]);
        if (nq2) {
          sc1[kt] = MFMA(khi, qh1[ks], sc1[kt]);
          sc1[kt] = MFMA(klo, qh1[ks], sc1[kt]);
          sc1[kt] = MFMA(khi, ql1[ks], sc1[kt]);
        }
      }
    }
    __builtin_amdgcn_s_setprio(0);
    sm_pv(sc0, m0, l0, acc0, VT);
    if (nq2) sm_pv(sc1, m1, l1, acc1, VT);
  };

  // ---- main loop: one barrier per tile ----
  load_t(0);
  cvt_t();
  write_t(0);
  if (nt > 1) load_t(1);
  asm volatile("s_waitcnt lgkmcnt(0)" ::: "memory");
  __builtin_amdgcn_s_barrier();

  for (int t = 0; t < nt; ++t) {
    const int cur = t & 1;
    if (t + 1 < nt) {
      cvt_t();                 // waits vmcnt for load(t+1) (1 tile of slack)
      write_t(cur ^ 1);        // safe: readers of cur^1 finished before last barrier
      if (t + 2 < nt) load_t(t + 2);
    }
    compute(cur);
    if (t + 1 < nt) {
      asm volatile("s_waitcnt lgkmcnt(0)" ::: "memory");
      __builtin_amdgcn_s_barrier();
    }
  }

  // ---- epilogue: normalize, store fp32 ----
  auto store_o = [&](const f32x4 (&af)[4], float lf, int qf) {
    const float linv = 1.0f / lf;
#pragma unroll
    for (int r = 0; r < 4; ++r) {
      const float lr = __shfl(linv, g * 4 + r);
      const int qrow = qf * 128 + w * 16 + g * 4 + r;
      float* op = outg + (size_t)(t0 + qrow) * RS + h * D + qj;
      op[0]  = af[0][r] * lr;
      op[16] = af[1][r] * lr;
      op[32] = af[2][r] * lr;
      op[48] = af[3][r] * lr;
    }
  };
  store_o(acc0, l0, 0);
  if (nq2) store_o(acc1, l1, 1);
}

extern "C" void kernel_launch(void* const* d_in, const int* in_sizes, int n_in,
                              void* d_out, int out_size, void* d_ws, size_t ws_size,
                              hipStream_t stream) {
  (void)in_sizes; (void)n_in; (void)d_ws; (void)ws_size; (void)out_size;
  const float* q  = (const float*)d_in[0];
  const float* k  = (const float*)d_in[1];
  const float* v  = (const float*)d_in[2];
  const int*   cu = (const int*)d_in[3];
  float* out = (float*)d_out;

  // one block per (seq, head): 128 * 16 = 2048 blocks, no dead blocks
  fa_mfma3_kernel<<<dim3(2048), dim3(512), 0, stream>>>(q, k, v, cu, out);
}

// Round 5
// 124.365 us; speedup vs baseline: 1.6527x; 1.6527x over previous
//
#include <hip/hip_runtime.h>
#include <hip/hip_bf16.h>

// FlashAttentionVarlen, bf16-MFMA flash attention, fp32 in/out.
// B=128 seqs (L in {128,256}), H=16, D=64, packed T=24576.
// Block = (seq b, head h, 128-row q chunk): 512 thr = 8 waves x 16 q rows.
// 64-key tiles, LDS double-buffered -> ONE barrier per tile; staging
// ds_writes overlap the previous tile's compute. K split bf16 hi/lo
// (QK error ~2^-17), V bf16-hi, P split hi/lo. Softmax in exp2 domain
// (log2e folded into Q prescale). Dispatch order puts both chunks of one
// (b,h) on the same XCD within 16 dispatches -> chunk1's K/V hits L2.

using bf16x8 = __attribute__((ext_vector_type(8))) short;
using u16x8  = __attribute__((ext_vector_type(8))) unsigned short;
using f32x4  = __attribute__((ext_vector_type(4))) float;

#define MFMA(a, b, c) __builtin_amdgcn_mfma_f32_16x16x32_bf16((a), (b), (c), 0, 0, 0)

constexpr int H  = 16;
constexpr int D  = 64;
constexpr int RS = H * D;                      // packed token row stride (floats)
constexpr float QSCALE = 0.125f * 1.44269504088896f;  // 1/sqrt(64) * log2(e)
constexpr float THR    = 11.5f;                // defer-max threshold (log2 units ~ 8 nats)

__device__ inline unsigned short bfbits(float x) {
  return __builtin_bit_cast(unsigned short, __float2bfloat16(x));
}
__device__ inline float bff(unsigned short u) {
  unsigned v = ((unsigned)u) << 16;
  return __builtin_bit_cast(float, v);
}

__global__ __launch_bounds__(512, 4)
void fa_mfma4_kernel(const float* __restrict__ qg, const float* __restrict__ kg,
                     const float* __restrict__ vg, const int* __restrict__ cu,
                     float* __restrict__ outg) {
  // double-buffered planes: K hi/lo [key][d] (slot ^= key&7), V^T [d][key] (slot ^= d&7)
  __shared__ unsigned short kph[2][64 * 64];
  __shared__ unsigned short kpl[2][64 * 64];
  __shared__ unsigned short vth[2][64 * 64];

  // XCD-pairing decode: 16-block groups = [8 pairs chunk0][same 8 pairs chunk1];
  // pair members are 8 apart (same XCD, round-robin) and temporally adjacent.
  const int bid   = (int)blockIdx.x;
  const int pp    = ((bid >> 4) << 3) + (bid & 7);   // pair id = b*16+h
  const int chunk = (bid >> 3) & 1;
  const int b = pp >> 4, h = pp & 15;

  const int t0 = cu[b];
  const int L  = cu[b + 1] - t0;
  if (chunk * 128 >= L) return;        // block-uniform early exit
  const int nt = L >> 6;               // 64-key tiles: 2 or 4

  const int tid = (int)threadIdx.x, lane = tid & 63, w = tid >> 6;
  const int g = lane >> 4, qj = lane & 15;

  // staging assignments (verified swizzles from R3)
  const int s_key = tid >> 3, s_d0 = (tid & 7) * 8;
  const int kidx  = s_key * 64 + (((s_d0 >> 3) ^ (s_key & 7)) << 3);
  const int s_vd  = tid & 63,  s_k0 = (tid >> 6) * 8;
  const int vidx  = s_vd * 64 + (((s_k0 >> 3) ^ (s_vd & 7)) << 3);

  const float* kbase = kg + (size_t)t0 * RS + h * D;
  const float* vbase = vg + (size_t)t0 * RS + h * D;

  // ---- Q fragments (B operand), split hi/lo, prescaled by QSCALE ----
  bf16x8 qh[2], ql[2];
  {
    const float* qrow = qg + (size_t)(t0 + chunk * 128 + w * 16 + qj) * RS + h * D;
#pragma unroll
    for (int ks = 0; ks < 2; ++ks) {
      const float4 f0 = *reinterpret_cast<const float4*>(qrow + ks * 32 + g * 8);
      const float4 f1 = *reinterpret_cast<const float4*>(qrow + ks * 32 + g * 8 + 4);
      const float f[8] = {f0.x, f0.y, f0.z, f0.w, f1.x, f1.y, f1.z, f1.w};
#pragma unroll
      for (int j = 0; j < 8; ++j) {
        const float x = f[j] * QSCALE;
        const unsigned short hs = bfbits(x);
        qh[ks][j] = (short)hs;
        ql[ks][j] = (short)bfbits(x - bff(hs));
      }
    }
  }

  f32x4 acc[4];
#pragma unroll
  for (int n = 0; n < 4; ++n) acc[n] = (f32x4){0.f, 0.f, 0.f, 0.f};
  float m = -1e30f, lsum = 0.f;

  // ---- staging: reg prefetch -> cvt -> ds_write (double-buffered) ----
  float4 ka, kb; float va[8];
  auto load_t = [&](int t) {
    const float* kr = kbase + (size_t)(t * 64 + s_key) * RS + s_d0;
    ka = *reinterpret_cast<const float4*>(kr);
    kb = *reinterpret_cast<const float4*>(kr + 4);
    const float* vp = vbase + (size_t)(t * 64 + s_k0) * RS + s_vd;
#pragma unroll
    for (int i = 0; i < 8; ++i) va[i] = vp[(size_t)i * RS];
  };
  auto cvt_write = [&](int buf) {
    u16x8 ch, cl, cv;
    const float kf[8] = {ka.x, ka.y, ka.z, ka.w, kb.x, kb.y, kb.z, kb.w};
#pragma unroll
    for (int i = 0; i < 8; ++i) {
      const unsigned short hs = bfbits(kf[i]);
      ch[i] = hs;
      cl[i] = bfbits(kf[i] - bff(hs));
    }
#pragma unroll
    for (int i = 0; i < 8; ++i) cv[i] = bfbits(va[i]);
    *reinterpret_cast<u16x8*>(&kph[buf][kidx]) = ch;
    *reinterpret_cast<u16x8*>(&kpl[buf][kidx]) = cl;
    *reinterpret_cast<u16x8*>(&vth[buf][vidx]) = cv;
  };

  // ---- compute one 64-key tile ----
  auto compute = [&](int buf) {
    const unsigned short* KH = kph[buf];
    const unsigned short* KL = kpl[buf];
    const unsigned short* VT = vth[buf];
    // QK^T (swapped): sc[kt] holds S[key=kt*16+g*4+r][q=qj] in log2 units
    f32x4 sc[4];
#pragma unroll
    for (int kt = 0; kt < 4; ++kt) sc[kt] = (f32x4){0.f, 0.f, 0.f, 0.f};
    __builtin_amdgcn_s_setprio(1);
#pragma unroll
    for (int kt = 0; kt < 4; ++kt) {
#pragma unroll
      for (int ks = 0; ks < 2; ++ks) {
        const int idx = (kt * 16 + qj) * 64 + (((ks * 4 + g) ^ (qj & 7)) << 3);
        const bf16x8 khi = *reinterpret_cast<const bf16x8*>(&KH[idx]);
        const bf16x8 klo = *reinterpret_cast<const bf16x8*>(&KL[idx]);
        sc[kt] = MFMA(khi, qh[ks], sc[kt]);
        sc[kt] = MFMA(klo, qh[ks], sc[kt]);
        sc[kt] = MFMA(khi, ql[ks], sc[kt]);
      }
    }
    __builtin_amdgcn_s_setprio(0);

    // online softmax (lane owns q=qj), exp2 domain, deferred max
    float tmax = sc[0][0];
#pragma unroll
    for (int kt = 0; kt < 4; ++kt)
#pragma unroll
      for (int r = 0; r < 4; ++r) tmax = fmaxf(tmax, sc[kt][r]);
    tmax = fmaxf(tmax, __shfl_xor(tmax, 16));
    tmax = fmaxf(tmax, __shfl_xor(tmax, 32));
    if (!__all(tmax <= m + THR)) {          // rare after first tile
      const float newm = fmaxf(m, tmax);
      const float corr = exp2f(m - newm);   // first tile: exp2(-huge)=0
      m = newm;
      lsum *= corr;
#pragma unroll
      for (int r = 0; r < 4; ++r) {
        const float cr = __shfl(corr, g * 4 + r);
#pragma unroll
        for (int n = 0; n < 4; ++n) acc[n][r] *= cr;
      }
    }
    float p[4][4], ps = 0.f;
#pragma unroll
    for (int kt = 0; kt < 4; ++kt)
#pragma unroll
      for (int r = 0; r < 4; ++r) {
        p[kt][r] = exp2f(sc[kt][r] - m);    // bounded by 2^11.5
        ps += p[kt][r];
      }
    ps += __shfl_xor(ps, 16);
    ps += __shfl_xor(ps, 32);
    lsum += ps;

    // PV per 32-key chunk: redistribute P (C->A layout), then MFMA
#pragma unroll
    for (int c = 0; c < 2; ++c) {
      bf16x8 pah, pal;
#pragma unroll
      for (int j = 0; j < 8; ++j) {
        const int sl  = (((2 * g + (j >> 2)) & 3) << 4) + qj;
        const float fa = __shfl(p[2 * c][j & 3], sl);
        const float fb = __shfl(p[2 * c + 1][j & 3], sl);
        const float pv = (g & 2) ? fb : fa;
        const unsigned short hb = bfbits(pv);
        pah[j] = (short)hb;
        pal[j] = (short)bfbits(pv - bff(hb));
      }
      __builtin_amdgcn_s_setprio(1);
#pragma unroll
      for (int n = 0; n < 4; ++n) {
        const int idx = (n * 16 + qj) * 64 + (((4 * c + g) ^ (qj & 7)) << 3);
        const bf16x8 vh = *reinterpret_cast<const bf16x8*>(&VT[idx]);
        acc[n] = MFMA(pah, vh, acc[n]);
        acc[n] = MFMA(pal, vh, acc[n]);
      }
      __builtin_amdgcn_s_setprio(0);
    }
  };

  // ---- main loop: one barrier per tile, dbuf LDS ----
  load_t(0);
  cvt_write(0);
  if (nt > 1) load_t(1);
  asm volatile("s_waitcnt lgkmcnt(0)" ::: "memory");
  __builtin_amdgcn_s_barrier();
  asm volatile("" ::: "memory");

  for (int t = 0; t < nt; ++t) {
    const int cur = t & 1;
    if (t + 1 < nt) {
      cvt_write(cur ^ 1);        // waits vmcnt for load(t+1); writes overlap compute
      if (t + 2 < nt) load_t(t + 2);
    }
    compute(cur);
    if (t + 1 < nt) {
      asm volatile("s_waitcnt lgkmcnt(0)" ::: "memory");
      __builtin_amdgcn_s_barrier();
      asm volatile("" ::: "memory");
    }
  }

  // ---- epilogue: normalize, store fp32 ----
  const float linv = 1.0f / lsum;
#pragma unroll
  for (int r = 0; r < 4; ++r) {
    const float lr = __shfl(linv, g * 4 + r);
    const int qrow = chunk * 128 + w * 16 + g * 4 + r;
    float* op = outg + (size_t)(t0 + qrow) * RS + h * D + qj;
    op[0]  = acc[0][r] * lr;
    op[16] = acc[1][r] * lr;
    op[32] = acc[2][r] * lr;
    op[48] = acc[3][r] * lr;
  }
}

extern "C" void kernel_launch(void* const* d_in, const int* in_sizes, int n_in,
                              void* d_out, int out_size, void* d_ws, size_t ws_size,
                              hipStream_t stream) {
  (void)in_sizes; (void)n_in; (void)d_ws; (void)ws_size; (void)out_size;
  const float* q  = (const float*)d_in[0];
  const float* k  = (const float*)d_in[1];
  const float* v  = (const float*)d_in[2];
  const int*   cu = (const int*)d_in[3];
  float* out = (float*)d_out;

  fa_mfma4_kernel<<<dim3(4096), dim3(512), 0, stream>>>(q, k, v, cu, out);
}